// Round 5
// baseline (514.398 us; speedup 1.0000x reference)
//
#include <hip/hip_runtime.h>

// Aggregator: scores = mean(ue*nr, dim); softmax over 32 neighbors;
// out = relu(mean(w * nv, neighbors)).  One wave per (b, iter) task.
// B=4096, NITER=8, NSIZE=32, DIM=64.
//
// Layout trick: the task's nr/nv tiles are 2048 floats = 512 float4.
// Lane l, step j loads float4 #(j*64 + l)  -> fully contiguous 1 KB per
// instruction. That float4 belongs to neighbor s = j*4 + (l>>4), dim quad
// q = l&15 (dims 4q..4q+3). All 17 loads issued before any compute.

constexpr int DIM = 64;
constexpr int NSIZE = 32;

__global__ __launch_bounds__(256) void Aggregator_kernel(
    const float* __restrict__ nv,   // [B, NITER*NSIZE, DIM]
    const float* __restrict__ nr,   // [B, NITER*NSIZE, DIM]
    const float* __restrict__ ue,   // [B, DIM]
    float* __restrict__ out,        // [B, NITER, DIM]
    int niter, int ntasks) {
  int wave = (int)((blockIdx.x * blockDim.x + threadIdx.x) >> 6);
  if (wave >= ntasks) return;
  int lane = (int)(threadIdx.x & 63);
  int b = wave / niter;
  int q = lane & 15;  // dim quad

  const float4* nr4 = (const float4*)(nr + (size_t)wave * (NSIZE * DIM));
  const float4* nv4 = (const float4*)(nv + (size_t)wave * (NSIZE * DIM));

  // ---- issue ALL loads up front (16.4 KB in flight per wave) ----
  float4 a[8], v[8];
#pragma unroll
  for (int j = 0; j < 8; ++j) a[j] = nr4[j * 64 + lane];
  float4 u = ((const float4*)(ue + (size_t)b * DIM))[q];
#pragma unroll
  for (int j = 0; j < 8; ++j) v[j] = nv4[j * 64 + lane];

  // ---- scores: partial dot over dims 4q..4q+3, reduce across the 16
  // lanes of the group (same neighbor, different q). sc[j] is the score of
  // neighbor j*4 + (lane>>4), replicated across its 16-lane group.
  float sc[8];
#pragma unroll
  for (int j = 0; j < 8; ++j) {
    float p = a[j].x * u.x;
    p = fmaf(a[j].y, u.y, p);
    p = fmaf(a[j].z, u.z, p);
    p = fmaf(a[j].w, u.w, p);
#pragma unroll
    for (int k = 1; k < 16; k <<= 1) p += __shfl_xor(p, k);
    sc[j] = p * (1.0f / DIM);
  }

  // ---- softmax over all 32 neighbors (8 local + cross-group 16,32) ----
  float m = sc[0];
#pragma unroll
  for (int j = 1; j < 8; ++j) m = fmaxf(m, sc[j]);
  m = fmaxf(m, __shfl_xor(m, 16));
  m = fmaxf(m, __shfl_xor(m, 32));
  float e[8];
  float z = 0.f;
#pragma unroll
  for (int j = 0; j < 8; ++j) {
    e[j] = __expf(sc[j] - m);
    z += e[j];
  }
  z += __shfl_xor(z, 16);
  z += __shfl_xor(z, 32);
  float inv = 1.0f / (z * (float)NSIZE);  // fold 1/NSIZE neighbor-mean in

  // ---- weighted accumulate: acc = sum_j w_j * nv4_j (dims 4q..4q+3,
  // neighbors {g, 4+g, ..., 28+g}), then cross-group reduce.
  float4 acc = make_float4(0.f, 0.f, 0.f, 0.f);
#pragma unroll
  for (int j = 0; j < 8; ++j) {
    float w = e[j] * inv;
    acc.x = fmaf(w, v[j].x, acc.x);
    acc.y = fmaf(w, v[j].y, acc.y);
    acc.z = fmaf(w, v[j].z, acc.z);
    acc.w = fmaf(w, v[j].w, acc.w);
  }
#pragma unroll
  for (int k = 16; k < 64; k <<= 1) {
    acc.x += __shfl_xor(acc.x, k);
    acc.y += __shfl_xor(acc.y, k);
    acc.z += __shfl_xor(acc.z, k);
    acc.w += __shfl_xor(acc.w, k);
  }

  if (lane < 16) {
    float4 r = make_float4(fmaxf(acc.x, 0.f), fmaxf(acc.y, 0.f),
                           fmaxf(acc.z, 0.f), fmaxf(acc.w, 0.f));
    ((float4*)(out + (size_t)wave * DIM))[q] = r;
  }
}

extern "C" void kernel_launch(void* const* d_in, const int* in_sizes, int n_in,
                              void* d_out, int out_size, void* d_ws, size_t ws_size,
                              hipStream_t stream) {
  // inputs: 0=self_vectors (unused), 1=neighbor_vectors, 2=neighbor_relations,
  //         3=user_embeddings, 4=neighbor_size (derived instead)
  const float* nv = (const float*)d_in[1];
  const float* nr = (const float*)d_in[2];
  const float* ue = (const float*)d_in[3];
  float* out = (float*)d_out;

  int ntasks = in_sizes[0] / DIM;         // B * NITER
  int niter  = in_sizes[0] / in_sizes[3]; // NITER
  int blocks = (ntasks + 3) / 4;          // 4 waves per 256-thread block
  Aggregator_kernel<<<blocks, 256, 0, stream>>>(nv, nr, ue, out, niter, ntasks);
}